// Round 19
// baseline (59.469 us; speedup 1.0000x reference)
//
#include <hip/hip_runtime.h>
#include <math.h>

// MaxofErosions2D, f-per-wave, SGPR taps, forced min3/max3, LDS store-transpose.
// out[b,h,w,f] = max_c min_{dy,dx} ( x[b,h+dy-2,w+dx-2,c] - kern[4-dy,4-dx,c,f] )
// x: (32,256,256,3) f32, kern: (5,5,3,8) f32, out: (32,256,256,8) f32.
//
// R19 = R18 with the right-halo staging bug fixed: window needs local cols
// 128,129 = LDS cols 130,131; R18 staged them at 134,135 (one-line fix).
//
//  - f-per-wave: block = 8 waves x (4 rows x 128 cols); wave w -> filter f=w.
//    Only 15 k taps live per dy, wave-uniform -> s_load/SGPR (free operand).
//  - forced v_min3_f32/v_max3_f32 via asm (no -ffast-math => fminf chains
//    don't auto-fuse; NaN-safe here: x,k finite, inf-k=inf).
//  - 8 px/lane: window = 9 ds_read_b128/dy shared across 8 px.
//  - stores via LDS transpose (smem reused after barrier) -> 2x float4/thread.

#define INFF __builtin_inff()

static __device__ __forceinline__ float min3f(float a, float b, float c) {
    float d;
    asm("v_min3_f32 %0, %1, %2, %3" : "=v"(d) : "v"(a), "v"(b), "v"(c));
    return d;
}
static __device__ __forceinline__ float max3f(float a, float b, float c) {
    float d;
    asm("v_max3_f32 %0, %1, %2, %3" : "=v"(d) : "v"(a), "v"(b), "v"(c));
    return d;
}

// LDS: phase 1-2: x tile [8 rows][408 f32] (136 cols x 3ch interleaved) = 3264
//      phase 3-4: out    [8 f][524]                                     = 4192
__global__ __launch_bounds__(512) void maxero_fw(
    const float* __restrict__ x,
    const float* __restrict__ kern,
    float* __restrict__ out)
{
    __shared__ __align__(16) float smem[4192];

    const int tid = threadIdx.x;
    const int bI  = blockIdx.x;          // 4096 blocks
    const int b   = bI >> 7;             // image 0..31
    const int rem = bI & 127;
    const int h0  = (rem >> 1) << 2;     // first output row, step 4
    const int c0  = (rem & 1) << 7;      // col tile: 0 or 128

    const float* xb = x + (size_t)b * (256 * 256 * 3);

    // ---- stage interior: 8 rows x 128 cols x 3ch = 768 float4 chunks
    #pragma unroll
    for (int k2 = 0; k2 < 2; ++k2) {
        int ch = tid + k2 * 512;
        if (ch < 768) {
            int rr = ch / 96;                 // 96 float4 per row
            int e  = ch - rr * 96;
            int gr = h0 - 2 + rr;
            bool rv = (unsigned)gr < 256u;
            int rc = min(max(gr, 0), 255);
            float4 v = *(const float4*)(xb + rc * 768 + c0 * 3 + e * 4);
            float* d = &smem[rr * 408 + 6 + e * 4];   // lds col 2 = local col 0
            ((float2*)d)[0] = rv ? make_float2(v.x, v.y) : make_float2(INFF, INFF);
            ((float2*)d)[1] = rv ? make_float2(v.z, v.w) : make_float2(INFF, INFF);
        }
    }
    // ---- halo: lds cols {0,1,130,131} x 8 rows x 3ch = 96 elems
    if (tid < 96) {
        int rr = tid / 12, q = tid - rr * 12;
        int cs = q / 3, c = q - cs * 3;
        int lcol = (cs < 2) ? cs : 128 + cs;               // 0,1,130,131 (FIXED)
        int gc   = (cs < 2) ? (c0 - 2 + cs) : (c0 + 126 + cs);  // -2,-1 / +128,+129
        int gr   = h0 - 2 + rr;
        bool v = ((unsigned)gr < 256u) && ((unsigned)gc < 256u);
        int rc = min(max(gr, 0), 255), cc = min(max(gc, 0), 255);
        smem[rr * 408 + lcol * 3 + c] = v ? xb[rc * 768 + cc * 3 + c] : INFF;
    }
    __syncthreads();

    const int lane = tid & 63;
    const int f    = __builtin_amdgcn_readfirstlane(tid >> 6);  // wave -> filter
    const int r    = lane >> 4;          // output row in tile, 0..3
    const int g    = lane & 15;          // col group: local cols 8g..8g+7

    float acc[8][3];
    #pragma unroll
    for (int p = 0; p < 8; ++p) { acc[p][0] = INFF; acc[p][1] = INFF; acc[p][2] = INFF; }

    #pragma unroll
    for (int dy = 0; dy < 5; ++dy) {
        // window: local cols 8g-2..8g+9 x 3ch = 36 f32, base byte 96g: aligned
        float xr[36];
        const float4* wp = (const float4*)&smem[(r + dy) * 408 + g * 24];
        #pragma unroll
        for (int q4 = 0; q4 < 9; ++q4) {
            float4 t = wp[q4];
            xr[q4*4+0] = t.x; xr[q4*4+1] = t.y; xr[q4*4+2] = t.z; xr[q4*4+3] = t.w;
        }
        // 15 wave-uniform taps -> s_load (kern + const offs, f in SGPR)
        float sk[15];
        #pragma unroll
        for (int dx = 0; dx < 5; ++dx)
            #pragma unroll
            for (int c = 0; c < 3; ++c)
                sk[dx * 3 + c] = kern[((4 - dy) * 5 + (4 - dx)) * 24 + c * 8 + f];
        #pragma unroll
        for (int c = 0; c < 3; ++c)
            #pragma unroll
            for (int p = 0; p < 8; ++p) {
                float d0 = xr[(p + 0) * 3 + c] - sk[0 * 3 + c];
                float d1 = xr[(p + 1) * 3 + c] - sk[1 * 3 + c];
                float d2 = xr[(p + 2) * 3 + c] - sk[2 * 3 + c];
                float d3 = xr[(p + 3) * 3 + c] - sk[3 * 3 + c];
                float d4 = xr[(p + 4) * 3 + c] - sk[4 * 3 + c];
                float a = min3f(acc[p][c], d0, d1);
                a = min3f(a, d2, d3);
                acc[p][c] = fminf(a, d4);
            }
    }

    // channel max (forced max3)
    float o[8];
    #pragma unroll
    for (int p = 0; p < 8; ++p) o[p] = max3f(acc[p][0], acc[p][1], acc[p][2]);

    __syncthreads();          // all xt reads done; smem becomes out buffer
    {
        float* ol = smem;     // [f][524]
        int px0 = r * 128 + 8 * g;
        ((float4*)&ol[f * 524 + px0])[0] = make_float4(o[0], o[1], o[2], o[3]);
        ((float4*)&ol[f * 524 + px0])[1] = make_float4(o[4], o[5], o[6], o[7]);
    }
    __syncthreads();
    {
        // thread t -> pixel px=t: gather 8 f (bank-staggered by pad 524), store 32B
        float v0 = smem[0 * 524 + tid], v1 = smem[1 * 524 + tid];
        float v2 = smem[2 * 524 + tid], v3 = smem[3 * 524 + tid];
        float v4 = smem[4 * 524 + tid], v5 = smem[5 * 524 + tid];
        float v6 = smem[6 * 524 + tid], v7 = smem[7 * 524 + tid];
        float* op = out + ((size_t)b * 65536
                           + (size_t)(h0 + (tid >> 7)) * 256
                           + c0 + (tid & 127)) * 8;
        ((float4*)op)[0] = make_float4(v0, v1, v2, v3);
        ((float4*)op)[1] = make_float4(v4, v5, v6, v7);
    }
}

extern "C" void kernel_launch(void* const* d_in, const int* in_sizes, int n_in,
                              void* d_out, int out_size, void* d_ws, size_t ws_size,
                              hipStream_t stream) {
    const float* x    = (const float*)d_in[0];
    const float* kern = (const float*)d_in[1];
    float* out        = (float*)d_out;
    maxero_fw<<<4096, 512, 0, stream>>>(x, kern, out);  // 32 img x 64 rowgrp x 2 colgrp
}